// Round 16
// baseline (85.895 us; speedup 1.0000x reference)
//
#include <hip/hip_runtime.h>
#include <hip/hip_bf16.h>
#include <math.h>

#define B_    8
#define T_    1024
#define C_    576
#define NH_   9
#define NKV_  3
#define HD_   64
#define KVC_  192
#define NREP_ 3
#define NQKV_ 960   // 576 + 192 + 192
#define NTK_  9     // K/64 tiles (K=576)

typedef __attribute__((ext_vector_type(8))) short bf16x8;
typedef __attribute__((ext_vector_type(4))) float f32x4;
typedef __attribute__((ext_vector_type(4))) int i32x4;

#define MFMA_16x16x32(a, b, c) __builtin_amdgcn_mfma_f32_16x16x32_bf16((a), (b), (c), 0, 0, 0)

__device__ __forceinline__ ushort f2bf(float f) {
  __hip_bfloat16 h = __float2bfloat16(f);
  return *reinterpret_cast<const ushort*>(&h);
}

// raw v_exp_f32 (2^x)
__device__ __forceinline__ float fexp2(float x) { return __builtin_amdgcn_exp2f(x); }

// swizzled ushort-index into a row-stride-64(bf16) tile (XOR bank swizzle)
__device__ __forceinline__ int swz(int row, int col) {
  int byte = (row << 7) + (col << 1);
  return (byte ^ ((row & 7) << 4)) >> 1;
}

// async 16B global->LDS (linear dest: wave-uniform base + lane*16)
__device__ __forceinline__ void gload16(const ushort* g, ushort* l) {
  __builtin_amdgcn_global_load_lds(
      (const __attribute__((address_space(1))) unsigned int*)g,
      (__attribute__((address_space(3))) unsigned int*)l, 16, 0, 0);
}

// 8 consecutive fp32 -> packed 8x bf16 (16B)
__device__ __forceinline__ i32x4 packrow(const float* src) {
  const float4 a = *reinterpret_cast<const float4*>(src);
  const float4 b = *reinterpret_cast<const float4*>(src + 4);
  union { ushort u[8]; i32x4 v; } t;
  t.u[0] = f2bf(a.x); t.u[1] = f2bf(a.y); t.u[2] = f2bf(a.z); t.u[3] = f2bf(a.w);
  t.u[4] = f2bf(b.x); t.u[5] = f2bf(b.y); t.u[6] = f2bf(b.z); t.u[7] = f2bf(b.w);
  return t.v;
}

// ---------------- x fp32 -> xb_t: tiled-swizzled bf16 A-tiles [tm][tk][128x64 swz] ----------------
__global__ __launch_bounds__(256) void convert_x_kernel(
    const float* __restrict__ x, ushort* __restrict__ xbt) {
  const int tm = blockIdx.x, tk = blockIdx.y;
  ushort* dst = xbt + ((size_t)tm * NTK_ + tk) * 8192;
  #pragma unroll
  for (int i = 0; i < 4; i++) {
    const int c = threadIdx.x + i * 256;
    const int row = c >> 3, colb = (c & 7) * 8;
    *reinterpret_cast<i32x4*>(&dst[swz(row, colb)]) =
        packrow(x + (size_t)(tm * 128 + row) * C_ + tk * 64 + colb);
  }
}

// ---------------- weights -> tiled-swizzled bf16 B-tiles + bias concat ----------------
__global__ __launch_bounds__(256) void convert_w_kernel(
    const float* __restrict__ Wq, const float* __restrict__ Wk,
    const float* __restrict__ Wv, const float* __restrict__ Wo,
    const float* __restrict__ bq, const float* __restrict__ bk,
    const float* __restrict__ bv, const float* __restrict__ bo,
    ushort* __restrict__ wqkvT, ushort* __restrict__ woT, float* __restrict__ bcat) {
  const int tnc = blockIdx.x, tk = blockIdx.y;
  #pragma unroll
  for (int i = 0; i < 2; i++) {
    const int c = threadIdx.x + i * 256;
    const int row = c >> 3, colb = (c & 7) * 8;
    const float* src; int ld; ushort* dst; int ncol;
    if (tnc < 15) {
      const int n = tnc * 64 + row;
      if (n < 576)      { src = Wq; ld = C_;  ncol = n; }
      else if (n < 768) { src = Wk; ld = KVC_; ncol = n - 576; }
      else              { src = Wv; ld = KVC_; ncol = n - 768; }
      dst = wqkvT + ((size_t)tnc * NTK_ + tk) * 4096;
    } else {
      src = Wo; ld = C_; ncol = (tnc - 15) * 64 + row;
      dst = woT + ((size_t)(tnc - 15) * NTK_ + tk) * 4096;
    }
    union { ushort u[8]; i32x4 v; } t;
    #pragma unroll
    for (int e = 0; e < 8; e++)
      t.u[e] = f2bf(src[(size_t)(tk * 64 + colb + e) * ld + ncol]);
    *reinterpret_cast<i32x4*>(&dst[swz(row, colb)]) = t.v;
    if (tk == 0 && (c & 7) == 0) {
      const int n = tnc * 64 + row;   // 0..1535
      float bv_;
      if (n < 576)       bv_ = bq[n];
      else if (n < 768)  bv_ = bk[n - 576];
      else if (n < 960)  bv_ = bv[n - 768];
      else               bv_ = bo[n - 960];
      bcat[n] = bv_;
    }
  }
}

// ---------------- bf16 MFMA GEMM, global_load_lds staging from pre-swizzled tiles ----------------
// MODE 0: fp32 row-major out + bias (O-proj). MODE 1: QKV split epilogue.
template<int MODE>
__global__ __launch_bounds__(256) void gemm_lds_kernel(
    const ushort* __restrict__ At, const ushort* __restrict__ Bt,
    const float* __restrict__ bias, void* __restrict__ Cp,
    ushort* __restrict__ ktv, ushort* __restrict__ vtv, int N) {
  const int nwg = gridDim.x * gridDim.y;
  const int flat = blockIdx.y * gridDim.x + blockIdx.x;
  const int wg = (flat & 7) * (nwg >> 3) + (flat >> 3);
  const int bxs = wg % gridDim.x, bys = wg / gridDim.x;

  __shared__ ushort As[128 * 64];
  __shared__ ushort Bs[64 * 64];
  const int bm = bys * 128, bn = bxs * 64;
  const int tid = threadIdx.x;
  const int wave = tid >> 6, lane = tid & 63;
  const int lg = lane >> 4, ll = lane & 15;
  const int wm = (wave >> 1) * 64, wn = (wave & 1) * 32;
  f32x4 acc[4][2] = {};

  const ushort* abase = At + (size_t)bys * NTK_ * 8192;
  const ushort* bbase = Bt + (size_t)bxs * NTK_ * 4096;

  for (int kt = 0; kt < NTK_; kt++) {
    const ushort* ak = abase + (size_t)kt * 8192;
    const ushort* bk = bbase + (size_t)kt * 4096;
    #pragma unroll
    for (int i = 0; i < 4; i++) {
      const int c0 = (wave << 6) + (i << 8);
      gload16(ak + (size_t)(c0 + lane) * 8, &As[c0 * 8]);
    }
    #pragma unroll
    for (int i = 0; i < 2; i++) {
      const int c0 = (wave << 6) + (i << 8);
      gload16(bk + (size_t)(c0 + lane) * 8, &Bs[c0 * 8]);
    }
    __syncthreads();

    bf16x8 af[4][2], bfr[2][2];
    #pragma unroll
    for (int mt = 0; mt < 4; mt++) {
      af[mt][0] = *reinterpret_cast<const bf16x8*>(&As[swz(wm + mt * 16 + ll, lg * 8)]);
      af[mt][1] = *reinterpret_cast<const bf16x8*>(&As[swz(wm + mt * 16 + ll, 32 + lg * 8)]);
    }
    #pragma unroll
    for (int nt = 0; nt < 2; nt++) {
      bfr[nt][0] = *reinterpret_cast<const bf16x8*>(&Bs[swz(wn + nt * 16 + ll, lg * 8)]);
      bfr[nt][1] = *reinterpret_cast<const bf16x8*>(&Bs[swz(wn + nt * 16 + ll, 32 + lg * 8)]);
    }
    #pragma unroll
    for (int mt = 0; mt < 4; mt++) {
      #pragma unroll
      for (int nt = 0; nt < 2; nt++) {
        acc[mt][nt] = MFMA_16x16x32(af[mt][0], bfr[nt][0], acc[mt][nt]);
        acc[mt][nt] = MFMA_16x16x32(af[mt][1], bfr[nt][1], acc[mt][nt]);
      }
    }
    __syncthreads();
  }

  #pragma unroll
  for (int mt = 0; mt < 4; mt++) {
    #pragma unroll
    for (int nt = 0; nt < 2; nt++) {
      const int col = bn + wn + nt * 16 + ll;
      #pragma unroll
      for (int r = 0; r < 4; r++) {
        const int row = bm + wm + mt * 16 + lg * 4 + r;
        const float val = acc[mt][nt][r] + bias[col];
        if (MODE == 0) {
          ((float*)Cp)[(size_t)row * N + col] = val;
        } else {
          if (col < 576) {
            ((ushort*)Cp)[(size_t)row * C_ + col] = f2bf(val * 0.18033688011112042f);
          } else if (col < 768) {
            const int kvh = (col - 576) >> 6, d = (col - 576) & 63;
            ushort* t = ktv + (((size_t)(row >> 10) * 3 + kvh) * 16 + ((row >> 6) & 15)) * 4096;
            t[swz(row & 63, d)] = f2bf(val);
          } else {
            const int kvh = (col - 768) >> 6, d = (col - 768) & 63;
            ushort* t = vtv + (((size_t)(row >> 10) * 3 + kvh) * 16 + ((row >> 6) & 15)) * 4096;
            t[swz(d, row & 63)] = f2bf(val);
          }
        }
      }
    }
  }
}

// ---------------- Causal GQA flash attention: barrier-free, K/V fragments direct from L1/L2 ----------------
// grid (NH, B, 16): qt = 15 - bz (longest first). 256 threads = 4 waves; wave w owns q-rows
// w*16..w*16+15 (lane q-row = w16+ll). K/V read per-lane straight from the pre-swizzled
// global tiles (same swz offsets the LDS path used) -> no staging, no __syncthreads at all.
__global__ __launch_bounds__(256) void attn_mfma_kernel(
    const ushort* __restrict__ qb, const ushort* __restrict__ ktv,
    const ushort* __restrict__ vtv, ushort* __restrict__ yt) {
  const int qt = 15 - blockIdx.z, h = blockIdx.x, b = blockIdx.y;
  const int kvh = h / NREP_;
  const int tid = threadIdx.x;
  const int wave = tid >> 6, lane = tid & 63;
  const int lg = lane >> 4, ll = lane & 15;
  const int w16 = wave << 4;
  const int qrow0 = qt << 6;
  const int nk = (qt + 2) >> 1;   // ceil((qt+1)*64 / 128)

  __shared__ ushort Ps[4][1024];    // per-wave P (reused across subs); only LDS in kernel

  const ushort* ktb = ktv + ((size_t)b * 3 + kvh) * 16 * 4096;
  const ushort* vtb = vtv + ((size_t)b * 3 + kvh) * 16 * 4096;

  // Q B-fragments straight from global (bf16, pre-scaled by 0.125*log2e)
  const ushort* qrow = qb + (size_t)(b * T_ + qrow0 + w16 + ll) * C_ + h * HD_;
  const bf16x8 qa0 = *reinterpret_cast<const bf16x8*>(qrow + lg * 8);
  const bf16x8 qa1 = *reinterpret_cast<const bf16x8*>(qrow + 32 + lg * 8);

  f32x4 o[4] = {};
  float m_i = -INFINITY, l_i = 0.f;   // log2-domain

  #pragma unroll 1
  for (int kt = 0; kt < nk; kt++) {
    const ushort* ksub0 = ktb + (size_t)(2 * kt) * 4096;
    const ushort* ksub1 = ksub0 + 4096;
    const ushort* vsub0 = vtb + (size_t)(2 * kt) * 4096;
    const ushort* vsub1 = vsub0 + 4096;

    // ---- S^T = K Q^T (16 MFMA): K fragments loaded per-lane from global tiles
    f32x4 s[8];
    #pragma unroll
    for (int kc = 0; kc < 8; kc++) {
      const ushort* kts = (kc < 4) ? ksub0 : ksub1;
      const int kcl = kc & 3;
      const bf16x8 kb0 = *reinterpret_cast<const bf16x8*>(&kts[swz(kcl * 16 + ll, lg * 8)]);
      const bf16x8 kb1 = *reinterpret_cast<const bf16x8*>(&kts[swz(kcl * 16 + ll, 32 + lg * 8)]);
      f32x4 z = {};
      z = MFMA_16x16x32(kb0, qa0, z);
      s[kc] = MFMA_16x16x32(kb1, qa1, z);
    }

    // ---- causal mask (last tile only)
    if (kt == nk - 1) {
      const int qg = qrow0 + w16 + ll - (kt << 7);
      #pragma unroll
      for (int kc = 0; kc < 8; kc++)
        #pragma unroll
        for (int r = 0; r < 4; r++)
          if (kc * 16 + lg * 4 + r > qg) s[kc][r] = -INFINITY;
    }

    // ---- online softmax (log2 domain), tree-max, defer-max
    float mA[8];
    #pragma unroll
    for (int kc = 0; kc < 8; kc++)
      mA[kc] = fmaxf(fmaxf(s[kc][0], s[kc][1]), fmaxf(s[kc][2], s[kc][3]));
    float t0 = fmaxf(fmaxf(fmaxf(mA[0], mA[1]), fmaxf(mA[2], mA[3])),
                     fmaxf(fmaxf(mA[4], mA[5]), fmaxf(mA[6], mA[7])));
    t0 = fmaxf(t0, __shfl_xor(t0, 16));
    t0 = fmaxf(t0, __shfl_xor(t0, 32));
    if (!__all(t0 <= m_i + 11.5415603f)) {
      const float mn = fmaxf(m_i, t0);
      const float al = fexp2(m_i - mn);
      m_i = mn;
      l_i *= al;
      #pragma unroll
      for (int r = 0; r < 4; r++) {
        const float ar = __shfl(al, lg * 4 + r);
        o[0][r] *= ar; o[1][r] *= ar; o[2][r] *= ar; o[3][r] *= ar;
      }
    }

    // ---- exp2 + P-write + PV, one 64-key sub-tile at a time (Ps per-wave, no barrier)
    float rsub[2];
    ushort* Pw = Ps[wave];
    #pragma unroll
    for (int sub = 0; sub < 2; sub++) {
      const ushort* vts = sub ? vsub1 : vsub0;
      float rk[4];
      #pragma unroll
      for (int kcl = 0; kcl < 4; kcl++) {
        const int kc = sub * 4 + kcl;
        float p0 = fexp2(s[kc][0] - m_i);
        float p1 = fexp2(s[kc][1] - m_i);
        float p2 = fexp2(s[kc][2] - m_i);
        float p3 = fexp2(s[kc][3] - m_i);
        rk[kcl] = (p0 + p1) + (p2 + p3);
        uint w01 = (uint)f2bf(p0) | ((uint)f2bf(p1) << 16);
        uint w23 = (uint)f2bf(p2) | ((uint)f2bf(p3) << 16);
        *reinterpret_cast<uint*>(&Pw[swz(ll, kcl * 16 + lg * 4)])     = w01;
        *reinterpret_cast<uint*>(&Pw[swz(ll, kcl * 16 + lg * 4 + 2)]) = w23;
      }
      rsub[sub] = (rk[0] + rk[1]) + (rk[2] + rk[3]);
      #pragma unroll
      for (int khl = 0; khl < 2; khl++) {
        const bf16x8 pa = *reinterpret_cast<const bf16x8*>(&Pw[swz(ll, khl * 32 + lg * 8)]);
        #pragma unroll
        for (int d0 = 0; d0 < 4; d0++) {
          const bf16x8 vbr = *reinterpret_cast<const bf16x8*>(&vts[swz(d0 * 16 + ll, khl * 32 + lg * 8)]);
          o[d0] = MFMA_16x16x32(pa, vbr, o[d0]);
        }
      }
    }
    float rs = rsub[0] + rsub[1];
    rs += __shfl_xor(rs, 16);
    rs += __shfl_xor(rs, 32);
    l_i += rs;
  }

  // ---- epilogue: y in tiled-swizzled A-layout for the O-projection GEMM
  #pragma unroll
  for (int r = 0; r < 4; r++) {
    const float lr = __shfl(l_i, lg * 4 + r);
    const float inv = 1.f / lr;
    const int rowg = b * T_ + qrow0 + w16 + lg * 4 + r;
    ushort* ybase = yt + ((size_t)(rowg >> 7) * NTK_ + h) * 8192;
    const int lrow = rowg & 127;
    #pragma unroll
    for (int d0 = 0; d0 < 4; d0++) {
      ybase[swz(lrow, d0 * 16 + ll)] = f2bf(o[d0][r] * inv);
    }
  }
}

extern "C" void kernel_launch(void* const* d_in, const int* in_sizes, int n_in,
                              void* d_out, int out_size, void* d_ws, size_t ws_size,
                              hipStream_t stream) {
  const float* x  = (const float*)d_in[0];
  const float* Wq = (const float*)d_in[1];
  const float* bq = (const float*)d_in[2];
  const float* Wk = (const float*)d_in[3];
  const float* bk = (const float*)d_in[4];
  const float* Wv = (const float*)d_in[5];
  const float* bv = (const float*)d_in[6];
  const float* Wo = (const float*)d_in[7];
  const float* bo = (const float*)d_in[8];
  float* out = (float*)d_out;

  const int M = B_ * T_;  // 8192
  ushort* wqkvT = (ushort*)d_ws;                           // 15*9*4096
  ushort* woT   = wqkvT + (size_t)15 * NTK_ * 4096;         // 9*9*4096
  float*  bcat  = (float*)(woT + (size_t)9 * NTK_ * 4096);  // [1536]
  ushort* qb    = (ushort*)(bcat + 1536);                   // [8192][576]
  ushort* ktv   = qb + (size_t)M * C_;                      // 8*3*16*4096
  ushort* vtv   = ktv + (size_t)B_ * NKV_ * 16 * 4096;      // 8*3*16*4096
  ushort* yt    = vtv + (size_t)B_ * NKV_ * 16 * 4096;      // tiled 64*9*8192
  ushort* xbt   = yt + (size_t)M * C_;                      // tiled 64*9*8192

  convert_w_kernel<<<dim3(24, NTK_), 256, 0, stream>>>(Wq, Wk, Wv, Wo, bq, bk, bv, bo,
                                                       wqkvT, woT, bcat);
  convert_x_kernel<<<dim3(M / 128, NTK_), 256, 0, stream>>>(x, xbt);
  gemm_lds_kernel<1><<<dim3(NQKV_ / 64, M / 128), 256, 0, stream>>>(
      xbt, wqkvT, bcat, qb, ktv, vtv, NQKV_);
  attn_mfma_kernel<<<dim3(NH_, B_, 16), 256, 0, stream>>>(qb, ktv, vtv, yt);
  gemm_lds_kernel<0><<<dim3(C_ / 64, M / 128), 256, 0, stream>>>(
      yt, woT, bcat + NQKV_, out, nullptr, nullptr, C_);
}

// Round 17
// 70.552 us; speedup vs baseline: 1.2175x; 1.2175x over previous
//
#include <hip/hip_runtime.h>
#include <hip/hip_bf16.h>
#include <math.h>

#define B_    8
#define T_    1024
#define C_    576
#define NH_   9
#define NKV_  3
#define HD_   64
#define KVC_  192
#define NREP_ 3
#define NQKV_ 960   // 576 + 192 + 192
#define NTK_  9     // K/64 tiles (K=576)

typedef __attribute__((ext_vector_type(8))) short bf16x8;
typedef __attribute__((ext_vector_type(4))) float f32x4;
typedef __attribute__((ext_vector_type(4))) int i32x4;

#define MFMA_16x16x32(a, b, c) __builtin_amdgcn_mfma_f32_16x16x32_bf16((a), (b), (c), 0, 0, 0)

__device__ __forceinline__ ushort f2bf(float f) {
  __hip_bfloat16 h = __float2bfloat16(f);
  return *reinterpret_cast<const ushort*>(&h);
}

// raw v_exp_f32 (2^x)
__device__ __forceinline__ float fexp2(float x) { return __builtin_amdgcn_exp2f(x); }

// swizzled ushort-index into a row-stride-64(bf16) tile (XOR bank swizzle)
__device__ __forceinline__ int swz(int row, int col) {
  int byte = (row << 7) + (col << 1);
  return (byte ^ ((row & 7) << 4)) >> 1;
}

// async 16B global->LDS (linear dest: wave-uniform base + lane*16)
__device__ __forceinline__ void gload16(const ushort* g, ushort* l) {
  __builtin_amdgcn_global_load_lds(
      (const __attribute__((address_space(1))) unsigned int*)g,
      (__attribute__((address_space(3))) unsigned int*)l, 16, 0, 0);
}

// 8 consecutive fp32 -> packed 8x bf16 (16B)
__device__ __forceinline__ i32x4 packrow(const float* src) {
  const float4 a = *reinterpret_cast<const float4*>(src);
  const float4 b = *reinterpret_cast<const float4*>(src + 4);
  union { ushort u[8]; i32x4 v; } t;
  t.u[0] = f2bf(a.x); t.u[1] = f2bf(a.y); t.u[2] = f2bf(a.z); t.u[3] = f2bf(a.w);
  t.u[4] = f2bf(b.x); t.u[5] = f2bf(b.y); t.u[6] = f2bf(b.z); t.u[7] = f2bf(b.w);
  return t.v;
}

// ---------------- x fp32 -> xb_t: tiled-swizzled bf16 A-tiles [tm][tk][128x64 swz] ----------------
__global__ __launch_bounds__(256) void convert_x_kernel(
    const float* __restrict__ x, ushort* __restrict__ xbt) {
  const int tm = blockIdx.x, tk = blockIdx.y;
  ushort* dst = xbt + ((size_t)tm * NTK_ + tk) * 8192;
  #pragma unroll
  for (int i = 0; i < 4; i++) {
    const int c = threadIdx.x + i * 256;
    const int row = c >> 3, colb = (c & 7) * 8;
    *reinterpret_cast<i32x4*>(&dst[swz(row, colb)]) =
        packrow(x + (size_t)(tm * 128 + row) * C_ + tk * 64 + colb);
  }
}

// ---------------- weights -> tiled-swizzled bf16 B-tiles + bias concat ----------------
__global__ __launch_bounds__(256) void convert_w_kernel(
    const float* __restrict__ Wq, const float* __restrict__ Wk,
    const float* __restrict__ Wv, const float* __restrict__ Wo,
    const float* __restrict__ bq, const float* __restrict__ bk,
    const float* __restrict__ bv, const float* __restrict__ bo,
    ushort* __restrict__ wqkvT, ushort* __restrict__ woT, float* __restrict__ bcat) {
  const int tnc = blockIdx.x, tk = blockIdx.y;
  #pragma unroll
  for (int i = 0; i < 2; i++) {
    const int c = threadIdx.x + i * 256;
    const int row = c >> 3, colb = (c & 7) * 8;
    const float* src; int ld; ushort* dst; int ncol;
    if (tnc < 15) {
      const int n = tnc * 64 + row;
      if (n < 576)      { src = Wq; ld = C_;  ncol = n; }
      else if (n < 768) { src = Wk; ld = KVC_; ncol = n - 576; }
      else              { src = Wv; ld = KVC_; ncol = n - 768; }
      dst = wqkvT + ((size_t)tnc * NTK_ + tk) * 4096;
    } else {
      src = Wo; ld = C_; ncol = (tnc - 15) * 64 + row;
      dst = woT + ((size_t)(tnc - 15) * NTK_ + tk) * 4096;
    }
    union { ushort u[8]; i32x4 v; } t;
    #pragma unroll
    for (int e = 0; e < 8; e++)
      t.u[e] = f2bf(src[(size_t)(tk * 64 + colb + e) * ld + ncol]);
    *reinterpret_cast<i32x4*>(&dst[swz(row, colb)]) = t.v;
    if (tk == 0 && (c & 7) == 0) {
      const int n = tnc * 64 + row;   // 0..1535
      float bv_;
      if (n < 576)       bv_ = bq[n];
      else if (n < 768)  bv_ = bk[n - 576];
      else if (n < 960)  bv_ = bv[n - 768];
      else               bv_ = bo[n - 960];
      bcat[n] = bv_;
    }
  }
}

// ---------------- bf16 MFMA GEMM, global_load_lds staging from pre-swizzled tiles ----------------
// MODE 0: fp32 row-major out + bias (O-proj). MODE 1: QKV split epilogue.
template<int MODE>
__global__ __launch_bounds__(256) void gemm_lds_kernel(
    const ushort* __restrict__ At, const ushort* __restrict__ Bt,
    const float* __restrict__ bias, void* __restrict__ Cp,
    ushort* __restrict__ ktv, ushort* __restrict__ vtv, int N) {
  const int nwg = gridDim.x * gridDim.y;
  const int flat = blockIdx.y * gridDim.x + blockIdx.x;
  const int wg = (flat & 7) * (nwg >> 3) + (flat >> 3);
  const int bxs = wg % gridDim.x, bys = wg / gridDim.x;

  __shared__ ushort As[128 * 64];
  __shared__ ushort Bs[64 * 64];
  const int bm = bys * 128, bn = bxs * 64;
  const int tid = threadIdx.x;
  const int wave = tid >> 6, lane = tid & 63;
  const int lg = lane >> 4, ll = lane & 15;
  const int wm = (wave >> 1) * 64, wn = (wave & 1) * 32;
  f32x4 acc[4][2] = {};

  const ushort* abase = At + (size_t)bys * NTK_ * 8192;
  const ushort* bbase = Bt + (size_t)bxs * NTK_ * 4096;

  for (int kt = 0; kt < NTK_; kt++) {
    const ushort* ak = abase + (size_t)kt * 8192;
    const ushort* bk = bbase + (size_t)kt * 4096;
    #pragma unroll
    for (int i = 0; i < 4; i++) {
      const int c0 = (wave << 6) + (i << 8);
      gload16(ak + (size_t)(c0 + lane) * 8, &As[c0 * 8]);
    }
    #pragma unroll
    for (int i = 0; i < 2; i++) {
      const int c0 = (wave << 6) + (i << 8);
      gload16(bk + (size_t)(c0 + lane) * 8, &Bs[c0 * 8]);
    }
    __syncthreads();

    bf16x8 af[4][2], bfr[2][2];
    #pragma unroll
    for (int mt = 0; mt < 4; mt++) {
      af[mt][0] = *reinterpret_cast<const bf16x8*>(&As[swz(wm + mt * 16 + ll, lg * 8)]);
      af[mt][1] = *reinterpret_cast<const bf16x8*>(&As[swz(wm + mt * 16 + ll, 32 + lg * 8)]);
    }
    #pragma unroll
    for (int nt = 0; nt < 2; nt++) {
      bfr[nt][0] = *reinterpret_cast<const bf16x8*>(&Bs[swz(wn + nt * 16 + ll, lg * 8)]);
      bfr[nt][1] = *reinterpret_cast<const bf16x8*>(&Bs[swz(wn + nt * 16 + ll, 32 + lg * 8)]);
    }
    #pragma unroll
    for (int mt = 0; mt < 4; mt++) {
      #pragma unroll
      for (int nt = 0; nt < 2; nt++) {
        acc[mt][nt] = MFMA_16x16x32(af[mt][0], bfr[nt][0], acc[mt][nt]);
        acc[mt][nt] = MFMA_16x16x32(af[mt][1], bfr[nt][1], acc[mt][nt]);
      }
    }
    __syncthreads();
  }

  #pragma unroll
  for (int mt = 0; mt < 4; mt++) {
    #pragma unroll
    for (int nt = 0; nt < 2; nt++) {
      const int col = bn + wn + nt * 16 + ll;
      #pragma unroll
      for (int r = 0; r < 4; r++) {
        const int row = bm + wm + mt * 16 + lg * 4 + r;
        const float val = acc[mt][nt][r] + bias[col];
        if (MODE == 0) {
          ((float*)Cp)[(size_t)row * N + col] = val;
        } else {
          if (col < 576) {
            ((ushort*)Cp)[(size_t)row * C_ + col] = f2bf(val * 0.18033688011112042f);
          } else if (col < 768) {
            const int kvh = (col - 576) >> 6, d = (col - 576) & 63;
            ushort* t = ktv + (((size_t)(row >> 10) * 3 + kvh) * 16 + ((row >> 6) & 15)) * 4096;
            t[swz(row & 63, d)] = f2bf(val);
          } else {
            const int kvh = (col - 768) >> 6, d = (col - 768) & 63;
            ushort* t = vtv + (((size_t)(row >> 10) * 3 + kvh) * 16 + ((row >> 6) & 15)) * 4096;
            t[swz(d, row & 63)] = f2bf(val);
          }
        }
      }
    }
  }
}

// ---------------- Causal GQA flash attention: dbuf K/V + counted vmcnt (T3/T4), KVBLK=64 ----------------
// grid (NH, B, 16): qt = 15 - bz (longest first). 256 threads = 4 waves; wave w owns q-rows
// w*16..w*16+15 (lane q-row = w16+ll). 64-key tiles double-buffered in LDS; next tile's
// global_load_lds stays IN FLIGHT across the barrier (s_waitcnt vmcnt(4), never 0 mid-loop).
__global__ __launch_bounds__(256) void attn_mfma_kernel(
    const ushort* __restrict__ qb, const ushort* __restrict__ ktv,
    const ushort* __restrict__ vtv, ushort* __restrict__ yt) {
  const int qt = 15 - blockIdx.z, h = blockIdx.x, b = blockIdx.y;
  const int kvh = h / NREP_;
  const int tid = threadIdx.x;
  const int wave = tid >> 6, lane = tid & 63;
  const int lg = lane >> 4, ll = lane & 15;
  const int w16 = wave << 4;
  const int qrow0 = qt << 6;
  const int ntile = qt + 1;   // 64-key tiles

  __shared__ ushort Ks[2][4096];    // dbuf: 64x64 swz key-major
  __shared__ ushort Vts[2][4096];   // dbuf: 64x64 swz d-major (transposed)
  __shared__ ushort Ps[4][1024];    // per-wave P

  const ushort* ktb = ktv + ((size_t)b * 3 + kvh) * 16 * 4096;
  const ushort* vtb = vtv + ((size_t)b * 3 + kvh) * 16 * 4096;

  // Q B-fragments straight from global (bf16, pre-scaled by 0.125*log2e)
  const ushort* qrow = qb + (size_t)(b * T_ + qrow0 + w16 + ll) * C_ + h * HD_;
  const bf16x8 qa0 = *reinterpret_cast<const bf16x8*>(qrow + lg * 8);
  const bf16x8 qa1 = *reinterpret_cast<const bf16x8*>(qrow + 32 + lg * 8);

  f32x4 o[4] = {};
  float m_i = -INFINITY, l_i = 0.f;   // log2-domain

  // ---- prologue: issue tile 0 into buf 0 (4 gloads/wave: 2 K + 2 V)
  {
    const ushort* ks = ktb;
    const ushort* vs = vtb;
    #pragma unroll
    for (int i = 0; i < 2; i++) {
      const int c0 = (wave << 6) + (i << 8);
      gload16(ks + (size_t)(c0 + lane) * 8, &Ks[0][c0 * 8]);
      gload16(vs + (size_t)(c0 + lane) * 8, &Vts[0][c0 * 8]);
    }
  }

  #pragma unroll 1
  for (int t = 0; t < ntile; t++) {
    const int cur = t & 1;
    // ---- issue next tile into the other buffer (stays in flight across barrier)
    if (t + 1 < ntile) {
      const ushort* ks = ktb + (size_t)(t + 1) * 4096;
      const ushort* vs = vtb + (size_t)(t + 1) * 4096;
      #pragma unroll
      for (int i = 0; i < 2; i++) {
        const int c0 = (wave << 6) + (i << 8);
        gload16(ks + (size_t)(c0 + lane) * 8, &Ks[cur ^ 1][c0 * 8]);
        gload16(vs + (size_t)(c0 + lane) * 8, &Vts[cur ^ 1][c0 * 8]);
      }
      asm volatile("s_waitcnt vmcnt(4)" ::: "memory");  // current tile's 4 landed; next 4 in flight
    } else {
      asm volatile("s_waitcnt vmcnt(0)" ::: "memory");
    }
    __builtin_amdgcn_s_barrier();   // all waves' current-tile loads confirmed -> tile ready

    // ---- S^T = K Q^T (8 MFMA): lane holds S[key=kcl*16+lg*4+r][q=w16+ll]
    f32x4 s[4];
    #pragma unroll
    for (int kcl = 0; kcl < 4; kcl++) {
      const bf16x8 kb0 = *reinterpret_cast<const bf16x8*>(&Ks[cur][swz(kcl * 16 + ll, lg * 8)]);
      const bf16x8 kb1 = *reinterpret_cast<const bf16x8*>(&Ks[cur][swz(kcl * 16 + ll, 32 + lg * 8)]);
      f32x4 z = {};
      z = MFMA_16x16x32(kb0, qa0, z);
      s[kcl] = MFMA_16x16x32(kb1, qa1, z);
    }

    // ---- causal mask (last tile only)
    if (t == ntile - 1) {
      const int qg = qrow0 + w16 + ll - (t << 6);
      #pragma unroll
      for (int kcl = 0; kcl < 4; kcl++)
        #pragma unroll
        for (int r = 0; r < 4; r++)
          if (kcl * 16 + lg * 4 + r > qg) s[kcl][r] = -INFINITY;
    }

    // ---- online softmax (log2 domain), tree-max, defer-max
    float mA[4];
    #pragma unroll
    for (int kcl = 0; kcl < 4; kcl++)
      mA[kcl] = fmaxf(fmaxf(s[kcl][0], s[kcl][1]), fmaxf(s[kcl][2], s[kcl][3]));
    float t0 = fmaxf(fmaxf(mA[0], mA[1]), fmaxf(mA[2], mA[3]));
    t0 = fmaxf(t0, __shfl_xor(t0, 16));
    t0 = fmaxf(t0, __shfl_xor(t0, 32));
    if (!__all(t0 <= m_i + 11.5415603f)) {
      const float mn = fmaxf(m_i, t0);
      const float al = fexp2(m_i - mn);
      m_i = mn;
      l_i *= al;
      #pragma unroll
      for (int r = 0; r < 4; r++) {
        const float ar = __shfl(al, lg * 4 + r);
        o[0][r] *= ar; o[1][r] *= ar; o[2][r] *= ar; o[3][r] *= ar;
      }
    }

    // ---- exp2 + P-write + PV (8 MFMA)
    float rk[4];
    ushort* Pw = Ps[wave];
    #pragma unroll
    for (int kcl = 0; kcl < 4; kcl++) {
      float p0 = fexp2(s[kcl][0] - m_i);
      float p1 = fexp2(s[kcl][1] - m_i);
      float p2 = fexp2(s[kcl][2] - m_i);
      float p3 = fexp2(s[kcl][3] - m_i);
      rk[kcl] = (p0 + p1) + (p2 + p3);
      uint w01 = (uint)f2bf(p0) | ((uint)f2bf(p1) << 16);
      uint w23 = (uint)f2bf(p2) | ((uint)f2bf(p3) << 16);
      *reinterpret_cast<uint*>(&Pw[swz(ll, kcl * 16 + lg * 4)])     = w01;
      *reinterpret_cast<uint*>(&Pw[swz(ll, kcl * 16 + lg * 4 + 2)]) = w23;
    }
    #pragma unroll
    for (int khl = 0; khl < 2; khl++) {
      const bf16x8 pa = *reinterpret_cast<const bf16x8*>(&Pw[swz(ll, khl * 32 + lg * 8)]);
      #pragma unroll
      for (int d0 = 0; d0 < 4; d0++) {
        const bf16x8 vbr = *reinterpret_cast<const bf16x8*>(&Vts[cur][swz(d0 * 16 + ll, khl * 32 + lg * 8)]);
        o[d0] = MFMA_16x16x32(pa, vbr, o[d0]);
      }
    }
    float rs = (rk[0] + rk[1]) + (rk[2] + rk[3]);
    rs += __shfl_xor(rs, 16);
    rs += __shfl_xor(rs, 32);
    l_i += rs;

    __builtin_amdgcn_s_barrier();   // all waves done reading buf[cur] before next iter stages into it
  }

  // ---- epilogue: y in tiled-swizzled A-layout for the O-projection GEMM
  #pragma unroll
  for (int r = 0; r < 4; r++) {
    const float lr = __shfl(l_i, lg * 4 + r);
    const float inv = 1.f / lr;
    const int rowg = b * T_ + qrow0 + w16 + lg * 4 + r;
    ushort* ybase = yt + ((size_t)(rowg >> 7) * NTK_ + h) * 8192;
    const int lrow = rowg & 127;
    #pragma unroll
    for (int d0 = 0; d0 < 4; d0++) {
      ybase[swz(lrow, d0 * 16 + ll)] = f2bf(o[d0][r] * inv);
    }
  }
}

extern "C" void kernel_launch(void* const* d_in, const int* in_sizes, int n_in,
                              void* d_out, int out_size, void* d_ws, size_t ws_size,
                              hipStream_t stream) {
  const float* x  = (const float*)d_in[0];
  const float* Wq = (const float*)d_in[1];
  const float* bq = (const float*)d_in[2];
  const float* Wk = (const float*)d_in[3];
  const float* bk = (const float*)d_in[4];
  const float* Wv = (const float*)d_in[5];
  const float* bv = (const float*)d_in[6];
  const float* Wo = (const float*)d_in[7];
  const float* bo = (const float*)d_in[8];
  float* out = (float*)d_out;

  const int M = B_ * T_;  // 8192
  ushort* wqkvT = (ushort*)d_ws;                           // 15*9*4096
  ushort* woT   = wqkvT + (size_t)15 * NTK_ * 4096;         // 9*9*4096
  float*  bcat  = (float*)(woT + (size_t)9 * NTK_ * 4096);  // [1536]
  ushort* qb    = (ushort*)(bcat + 1536);                   // [8192][576]
  ushort* ktv   = qb + (size_t)M * C_;                      // 8*3*16*4096
  ushort* vtv   = ktv + (size_t)B_ * NKV_ * 16 * 4096;      // 8*3*16*4096
  ushort* yt    = vtv + (size_t)B_ * NKV_ * 16 * 4096;      // tiled 64*9*8192
  ushort* xbt   = yt + (size_t)M * C_;                      // tiled 64*9*8192

  convert_w_kernel<<<dim3(24, NTK_), 256, 0, stream>>>(Wq, Wk, Wv, Wo, bq, bk, bv, bo,
                                                       wqkvT, woT, bcat);
  convert_x_kernel<<<dim3(M / 128, NTK_), 256, 0, stream>>>(x, xbt);
  gemm_lds_kernel<1><<<dim3(NQKV_ / 64, M / 128), 256, 0, stream>>>(
      xbt, wqkvT, bcat, qb, ktv, vtv, NQKV_);
  attn_mfma_kernel<<<dim3(NH_, B_, 16), 256, 0, stream>>>(qb, ktv, vtv, yt);
  gemm_lds_kernel<0><<<dim3(C_ / 64, M / 128), 256, 0, stream>>>(
      yt, woT, bcat + NQKV_, out, nullptr, nullptr, C_);
}